// Round 3
// baseline (93.514 us; speedup 1.0000x reference)
//
#include <hip/hip_runtime.h>
#include <math.h>

#define BLK 256
#define SPT 2              // samples per thread
#define SPB (BLK * SPT)    // 512 samples per block

// d_ws float offsets (all 16B-aligned rows)
#define OFF_W1 0           // 15 rows x 8  (7 used + pad)
#define OFF_W2 128         // 15 rows x 16 (15 used + pad)
#define OFF_W3 384         // 7 rows x 16
#define OFF_B1 512
#define OFF_B2 528
#define OFF_B3 544
#define OFF_FK 560         // 7 x 8 : {ca, sa, a, d, off, d*sa, d*ca, 0}
#define WS_FLOATS 616

// tanh(x) = 1 - 2/(e^{2x}+1); clamp so __expf never overflows.
__device__ __forceinline__ float fast_tanh(float x) {
    x = fminf(9.0f, fmaxf(-9.0f, x));
    float e = __expf(2.0f * x);
    return fmaf(-2.0f, __frcp_rn(e + 1.0f), 1.0f);
}

// hw v_sin/v_cos operate on revolutions; reduce with fract.
__device__ __forceinline__ void fast_sincos(float x, float& s, float& c) {
    const float INV2PI = 0.15915494309189535f;
    float r = x * INV2PI;
    r = r - floorf(r);
    s = __builtin_amdgcn_sinf(r);
    c = __builtin_amdgcn_cosf(r);
}

// One tiny block: repack weights into aligned padded rows + precompute fk trig.
__global__ __launch_bounds__(BLK) void pack_kernel(
    const float* __restrict__ fk, const float* __restrict__ W1,
    const float* __restrict__ b1, const float* __restrict__ W2,
    const float* __restrict__ b2, const float* __restrict__ W3,
    const float* __restrict__ b3, float* __restrict__ ws)
{
    const int t = threadIdx.x;
    for (int i = t; i < WS_FLOATS; i += BLK) ws[i] = 0.0f;
    __syncthreads();
    for (int i = t; i < 120; i += BLK) { int r = i >> 3, c = i & 7;  if (c < 7)  ws[OFF_W1 + i] = W1[r * 7  + c]; }
    for (int i = t; i < 240; i += BLK) { int r = i >> 4, c = i & 15; if (c < 15) ws[OFF_W2 + i] = W2[r * 15 + c]; }
    for (int i = t; i < 112; i += BLK) { int r = i >> 4, c = i & 15; if (c < 15) ws[OFF_W3 + i] = W3[r * 15 + c]; }
    if (t < 15) { ws[OFF_B1 + t] = b1[t]; ws[OFF_B2 + t] = b2[t]; }
    if (t < 7) {
        ws[OFF_B3 + t] = b3[t];
        float al = fk[4 * t], a = fk[4 * t + 1], d = fk[4 * t + 2], off = fk[4 * t + 3];
        float sa = sinf(al), ca = cosf(al);          // precise, once
        float* p = ws + OFF_FK + 8 * t;
        p[0] = ca; p[1] = sa; p[2] = a; p[3] = d; p[4] = off;
        p[5] = d * sa; p[6] = d * ca; p[7] = 0.0f;
    }
}

__global__ __launch_bounds__(BLK) void fk_main(
    const float* __restrict__ joints, const float* __restrict__ wsf,
    float* __restrict__ out, int B)
{
    const float4* __restrict__ w4 = (const float4*)wsf;
    __shared__ float sJ[SPB * 7];                    // 14336 B; reused for output
    const int t = threadIdx.x;
    const int base = blockIdx.x * SPB;               // first sample of block
    const int rem = B - base;                        // samples left

    // ---- stage joints, coalesced (float4 fast path for full blocks) ----
    if (rem >= SPB) {
        const float4* gsrc = (const float4*)(joints + base * 7);
        float4* ldst = (float4*)sJ;
        #pragma unroll
        for (int i = 0; i < (SPB * 7) / (4 * BLK); ++i) ldst[t + i * BLK] = gsrc[t + i * BLK];
        { int i = ((SPB * 7) / (4 * BLK)) * BLK + t; if (i < (SPB * 7) / 4) ldst[i] = gsrc[i]; }
    } else {
        const int nval = rem * 7;
        for (int i = t; i < nval; i += BLK) sJ[i] = joints[base * 7 + i];
    }
    __syncthreads();

    float j[SPT][7];
    float r[SPT][3][4];
    bool valid[SPT];

    #pragma unroll
    for (int s = 0; s < SPT; ++s) {
        const int ss = t + s * BLK;
        valid[s] = (base + ss) < B;
        #pragma unroll
        for (int k = 0; k < 7; ++k) j[s][k] = valid[s] ? sJ[ss * 7 + k] : 0.0f;
    }

    // ---- layer 1: 7 -> 15 ----
    float h1[SPT][15];
    #pragma unroll
    for (int i = 0; i < 15; ++i) {
        const float4 wa = w4[(OFF_W1 >> 2) + 2 * i];
        const float4 wb = w4[(OFF_W1 >> 2) + 2 * i + 1];
        const float bi = wsf[OFF_B1 + i];
        #pragma unroll
        for (int s = 0; s < SPT; ++s) {
            float a0 = bi;
            a0 = fmaf(j[s][0], wa.x, a0); a0 = fmaf(j[s][1], wa.y, a0);
            a0 = fmaf(j[s][2], wa.z, a0); a0 = fmaf(j[s][3], wa.w, a0);
            a0 = fmaf(j[s][4], wb.x, a0); a0 = fmaf(j[s][5], wb.y, a0);
            a0 = fmaf(j[s][6], wb.z, a0);
            h1[s][i] = fast_tanh(a0);
        }
    }
    // ---- layer 2: 15 -> 15 ----
    float h2[SPT][15];
    #pragma unroll
    for (int i = 0; i < 15; ++i) {
        const float4 wa = w4[(OFF_W2 >> 2) + 4 * i + 0];
        const float4 wb = w4[(OFF_W2 >> 2) + 4 * i + 1];
        const float4 wc = w4[(OFF_W2 >> 2) + 4 * i + 2];
        const float4 wd = w4[(OFF_W2 >> 2) + 4 * i + 3];
        const float bi = wsf[OFF_B2 + i];
        #pragma unroll
        for (int s = 0; s < SPT; ++s) {
            float a0 = bi;
            a0 = fmaf(h1[s][0],  wa.x, a0); a0 = fmaf(h1[s][1],  wa.y, a0);
            a0 = fmaf(h1[s][2],  wa.z, a0); a0 = fmaf(h1[s][3],  wa.w, a0);
            a0 = fmaf(h1[s][4],  wb.x, a0); a0 = fmaf(h1[s][5],  wb.y, a0);
            a0 = fmaf(h1[s][6],  wb.z, a0); a0 = fmaf(h1[s][7],  wb.w, a0);
            a0 = fmaf(h1[s][8],  wc.x, a0); a0 = fmaf(h1[s][9],  wc.y, a0);
            a0 = fmaf(h1[s][10], wc.z, a0); a0 = fmaf(h1[s][11], wc.w, a0);
            a0 = fmaf(h1[s][12], wd.x, a0); a0 = fmaf(h1[s][13], wd.y, a0);
            a0 = fmaf(h1[s][14], wd.z, a0);
            h2[s][i] = fast_tanh(a0);
        }
    }
    // ---- layer 3 (7 outputs) fused with DH chain ----
    #pragma unroll
    for (int jj = 0; jj < 7; ++jj) {
        const float4 wa = w4[(OFF_W3 >> 2) + 4 * jj + 0];
        const float4 wb = w4[(OFF_W3 >> 2) + 4 * jj + 1];
        const float4 wc = w4[(OFF_W3 >> 2) + 4 * jj + 2];
        const float4 wd = w4[(OFF_W3 >> 2) + 4 * jj + 3];
        const float bi  = wsf[OFF_B3 + jj];
        const float ca  = wsf[OFF_FK + 8 * jj + 0];
        const float sa  = wsf[OFF_FK + 8 * jj + 1];
        const float a   = wsf[OFF_FK + 8 * jj + 2];
        const float off = wsf[OFF_FK + 8 * jj + 4];
        const float dsa = wsf[OFF_FK + 8 * jj + 5];
        const float dca = wsf[OFF_FK + 8 * jj + 6];
        #pragma unroll
        for (int s = 0; s < SPT; ++s) {
            float a0 = bi;
            a0 = fmaf(h2[s][0],  wa.x, a0); a0 = fmaf(h2[s][1],  wa.y, a0);
            a0 = fmaf(h2[s][2],  wa.z, a0); a0 = fmaf(h2[s][3],  wa.w, a0);
            a0 = fmaf(h2[s][4],  wb.x, a0); a0 = fmaf(h2[s][5],  wb.y, a0);
            a0 = fmaf(h2[s][6],  wb.w == 0.0f ? wb.w : wb.w, a0); // placeholder never taken
            a0 = fmaf(h2[s][6],  0.0f, a0);                        // (see below)
            a0 = a0; // corrected explicit sequence follows
            // NOTE: rewrite cleanly to avoid mistakes:
            a0 = bi;
            a0 = fmaf(h2[s][0],  wa.x, a0); a0 = fmaf(h2[s][1],  wa.y, a0);
            a0 = fmaf(h2[s][2],  wa.z, a0); a0 = fmaf(h2[s][3],  wa.w, a0);
            a0 = fmaf(h2[s][4],  wb.x, a0); a0 = fmaf(h2[s][5],  wb.y, a0);
            a0 = fmaf(h2[s][6],  wb.z, a0); a0 = fmaf(h2[s][7],  wb.w, a0);
            a0 = fmaf(h2[s][8],  wc.x, a0); a0 = fmaf(h2[s][9],  wc.y, a0);
            a0 = fmaf(h2[s][10], wc.z, a0); a0 = fmaf(h2[s][11], wc.w, a0);
            a0 = fmaf(h2[s][12], wd.x, a0); a0 = fmaf(h2[s][13], wd.y, a0);
            a0 = fmaf(h2[s][14], wd.z, a0);
            const float corr = fast_tanh(a0);
            const float th = j[s][jj] + corr + off;
            float st, ct;
            fast_sincos(th, st, ct);
            // M rows: m0=[ct,-st,0,a] m1=[st*ca,ct*ca,-sa,-dsa] m2=[st*sa,ct*sa,ca,dca]
            const float m10 = st * ca, m11 = ct * ca;
            const float m20 = st * sa, m21 = ct * sa;
            if (jj == 0) {
                r[s][0][0] = ct;  r[s][0][1] = -st;  r[s][0][2] = 0.0f; r[s][0][3] = a;
                r[s][1][0] = m10; r[s][1][1] = m11;  r[s][1][2] = -sa;  r[s][1][3] = -dsa;
                r[s][2][0] = m20; r[s][2][1] = m21;  r[s][2][2] = ca;   r[s][2][3] = dca;
            } else {
                #pragma unroll
                for (int i = 0; i < 3; ++i) {
                    const float e0 = r[s][i][0], e1 = r[s][i][1], e2 = r[s][i][2], e3 = r[s][i][3];
                    r[s][i][0] = e0 * ct + e1 * m10 + e2 * m20;
                    r[s][i][1] = -e0 * st + e1 * m11 + e2 * m21;
                    r[s][i][2] = e1 * -sa + e2 * ca;
                    r[s][i][3] = e0 * a + e1 * -dsa + e2 * dca + e3;
                }
            }
        }
    }

    // ---- stage outputs through LDS, write coalesced ----
    __syncthreads();
    #pragma unroll
    for (int s = 0; s < SPT; ++s) {
        const int ss = t + s * BLK;
        if (valid[s]) {
            sJ[ss * 3 + 0] = r[s][0][3];
            sJ[ss * 3 + 1] = r[s][1][3];
            sJ[ss * 3 + 2] = r[s][2][3];
        }
    }
    __syncthreads();
    const int onval = min(SPB * 3, (B - base) * 3);
    if (onval == SPB * 3) {
        float4* gdst = (float4*)(out + base * 3);
        const float4* lsrc = (const float4*)sJ;
        #pragma unroll
        for (int i = 0; i < (SPB * 3) / (4 * BLK); ++i) gdst[t + i * BLK] = lsrc[t + i * BLK];
        { int i = ((SPB * 3) / (4 * BLK)) * BLK + t; if (i < (SPB * 3) / 4) gdst[i] = lsrc[i]; }
    } else {
        for (int i = t; i < onval; i += BLK) out[base * 3 + i] = sJ[i];
    }
}

extern "C" void kernel_launch(void* const* d_in, const int* in_sizes, int n_in,
                              void* d_out, int out_size, void* d_ws, size_t ws_size,
                              hipStream_t stream) {
    const float* joints    = (const float*)d_in[0];
    const float* fk_params = (const float*)d_in[1];
    const float* W1 = (const float*)d_in[2];
    const float* b1 = (const float*)d_in[3];
    const float* W2 = (const float*)d_in[4];
    const float* b2 = (const float*)d_in[5];
    const float* W3 = (const float*)d_in[6];
    const float* b3 = (const float*)d_in[7];
    float* out = (float*)d_out;
    float* ws  = (float*)d_ws;

    const int B = in_sizes[0] / 7;
    pack_kernel<<<1, BLK, 0, stream>>>(fk_params, W1, b1, W2, b2, W3, b3, ws);
    const int nblk = (B + SPB - 1) / SPB;
    fk_main<<<nblk, BLK, 0, stream>>>(joints, ws, out, B);
}

// Round 4
// 79.625 us; speedup vs baseline: 1.1744x; 1.1744x over previous
//
#include <hip/hip_runtime.h>
#include <math.h>

#define BLK 256

// tanh(x) = 1 - 2/(e^{2x}+1); clamp so __expf never overflows.
// v_rcp_f32 is ~1 ulp — fine at this problem's tolerance.
__device__ __forceinline__ float fast_tanh(float x) {
    x = fminf(9.0f, fmaxf(-9.0f, x));
    float e = __expf(2.0f * x);
    return fmaf(-2.0f, __builtin_amdgcn_rcpf(e + 1.0f), 1.0f);
}

// hw v_sin/v_cos operate on revolutions; v_fract does the range reduction.
__device__ __forceinline__ void fast_sincos(float x, float& s, float& c) {
    const float INV2PI = 0.15915494309189535f;
    float r = __builtin_amdgcn_fractf(x * INV2PI);
    s = __builtin_amdgcn_sinf(r);
    c = __builtin_amdgcn_cosf(r);
}

__global__ __launch_bounds__(BLK) void fk_fused_kernel(
    const float* __restrict__ joints,    // [B,7]
    const float* __restrict__ fk_params, // [7,4] : alpha, a, d, offset
    const float* __restrict__ W1, const float* __restrict__ b1,  // [15,7],[15]
    const float* __restrict__ W2, const float* __restrict__ b2,  // [15,15],[15]
    const float* __restrict__ W3, const float* __restrict__ b3,  // [7,15],[7]
    float* __restrict__ out,             // [B,3]
    int B)
{
    __shared__ float sJ[BLK * 7];   // joints staging, reused for output staging

    const int t = threadIdx.x;
    const int base = blockIdx.x * BLK;
    const bool full = (B - base) >= BLK;   // uniform per block

    // ---- stage this block's joints, coalesced ----
    if (full) {
        // BLK*7 floats = 448 float4s, BLK threads -> 1.75 iters; do 2 guarded
        const float4* gsrc = (const float4*)(joints + base * 7);
        float4* ldst = (float4*)sJ;
        ldst[t] = gsrc[t];
        { int i = t + BLK; if (i < (BLK * 7) / 4) ldst[i] = gsrc[i]; }
    } else {
        const int nval = (B - base) * 7;
        for (int i = t; i < nval; i += BLK) sJ[i] = joints[base * 7 + i];
    }
    __syncthreads();

    const int sample = base + t;
    const bool active = full || (sample < B);
    float r0[4], r1[4], r2[4];   // rows 0..2 of ee (row 3 stays [0,0,0,1])

    if (active) {
        float j[7];
        #pragma unroll
        for (int k = 0; k < 7; ++k) j[k] = sJ[t * 7 + k];

        // ---- layer 1: 7 -> 15. Weights wave-uniform -> scalar loads. ----
        float h1[15];
        #pragma unroll
        for (int i = 0; i < 15; ++i) {
            float s = b1[i];
            #pragma unroll
            for (int k = 0; k < 7; ++k) s = fmaf(j[k], W1[i * 7 + k], s);
            h1[i] = fast_tanh(s);
        }
        // ---- layer 2: 15 -> 15 ----
        float h2[15];
        #pragma unroll
        for (int i = 0; i < 15; ++i) {
            float s = b2[i];
            #pragma unroll
            for (int k = 0; k < 15; ++k) s = fmaf(h1[k], W2[i * 15 + k], s);
            h2[i] = fast_tanh(s);
        }

        // ---- layer 3 (7 outputs) fused with DH chain ----
        #pragma unroll
        for (int jj = 0; jj < 7; ++jj) {
            float s = b3[jj];
            #pragma unroll
            for (int k = 0; k < 15; ++k) s = fmaf(h2[k], W3[jj * 15 + k], s);
            float corr = fast_tanh(s);

            const float alpha = fk_params[jj * 4 + 0];
            const float a     = fk_params[jj * 4 + 1];
            const float d     = fk_params[jj * 4 + 2];
            const float off   = fk_params[jj * 4 + 3];

            float th = j[jj] + corr + off;
            float st, ct, sa, ca;
            fast_sincos(th, st, ct);
            fast_sincos(alpha, sa, ca);

            // M rows: m0=[ct,-st,0,a]  m1=[st*ca,ct*ca,-sa,-d*sa]  m2=[st*sa,ct*sa,ca,ca*d]
            const float m10 = st * ca, m11 = ct * ca, m13 = -d * sa;
            const float m20 = st * sa, m21 = ct * sa, m23 = ca * d;
            if (jj == 0) {
                r0[0] = ct;  r0[1] = -st; r0[2] = 0.0f; r0[3] = a;
                r1[0] = m10; r1[1] = m11; r1[2] = -sa;  r1[3] = m13;
                r2[0] = m20; r2[1] = m21; r2[2] = ca;   r2[3] = m23;
            } else {
                #pragma unroll
                for (int i = 0; i < 1; ++i) { } // keep structure flat below
                float n0, n1, n2, n3;
                n0 = r0[0]*ct + r0[1]*m10 + r0[2]*m20;
                n1 = -r0[0]*st + r0[1]*m11 + r0[2]*m21;
                n2 =             r0[1]*-sa + r0[2]*ca;
                n3 = r0[0]*a  + r0[1]*m13 + r0[2]*m23 + r0[3];
                r0[0]=n0; r0[1]=n1; r0[2]=n2; r0[3]=n3;
                n0 = r1[0]*ct + r1[1]*m10 + r1[2]*m20;
                n1 = -r1[0]*st + r1[1]*m11 + r1[2]*m21;
                n2 =             r1[1]*-sa + r1[2]*ca;
                n3 = r1[0]*a  + r1[1]*m13 + r1[2]*m23 + r1[3];
                r1[0]=n0; r1[1]=n1; r1[2]=n2; r1[3]=n3;
                n0 = r2[0]*ct + r2[1]*m10 + r2[2]*m20;
                n1 = -r2[0]*st + r2[1]*m11 + r2[2]*m21;
                n2 =             r2[1]*-sa + r2[2]*ca;
                n3 = r2[0]*a  + r2[1]*m13 + r2[2]*m23 + r2[3];
                r2[0]=n0; r2[1]=n1; r2[2]=n2; r2[3]=n3;
            }
        }
    }

    // ---- stage outputs through LDS, write coalesced ----
    __syncthreads();           // done reading sJ as joints
    if (active) {
        sJ[t * 3 + 0] = r0[3];
        sJ[t * 3 + 1] = r1[3];
        sJ[t * 3 + 2] = r2[3];
    }
    __syncthreads();
    if (full) {
        // BLK*3 floats = 192 float4s
        float4* gdst = (float4*)(out + base * 3);
        const float4* lsrc = (const float4*)sJ;
        if (t < (BLK * 3) / 4) gdst[t] = lsrc[t];
    } else {
        const int onval = (B - base) * 3;
        for (int i = t; i < onval; i += BLK) out[base * 3 + i] = sJ[i];
    }
}

extern "C" void kernel_launch(void* const* d_in, const int* in_sizes, int n_in,
                              void* d_out, int out_size, void* d_ws, size_t ws_size,
                              hipStream_t stream) {
    const float* joints    = (const float*)d_in[0];
    const float* fk_params = (const float*)d_in[1];
    const float* W1 = (const float*)d_in[2];
    const float* b1 = (const float*)d_in[3];
    const float* W2 = (const float*)d_in[4];
    const float* b2 = (const float*)d_in[5];
    const float* W3 = (const float*)d_in[6];
    const float* b3 = (const float*)d_in[7];
    float* out = (float*)d_out;

    const int B = in_sizes[0] / 7;
    const int nblk = (B + BLK - 1) / BLK;
    fk_fused_kernel<<<nblk, BLK, 0, stream>>>(joints, fk_params, W1, b1, W2, b2,
                                              W3, b3, out, B);
}